// Round 11
// baseline (1048.939 us; speedup 1.0000x reference)
//
#include <hip/hip_runtime.h>
#include <math.h>

#define BB 4
#define Cc 64
#define C2 128
#define C6 384
#define HW 65536
#define EPS 1e-6f
#define CST 68      // padded LDS channel stride (patch kernel)
#define OSPLIT 12   // output-channel split across blocks
#define CHB 32      // channels per block = 384/OSPLIT
#define HCH 16      // channels per dw-exchange chunk (2 chunks)
#define HPAD 20     // hs row stride in floats: 8 distinct bank-quad starts -> conflict-free b128
#define TW 16       // tile width (cols), interior 14
#define TH 32       // tile height (rows), interior 30

// ---------------- K0: RoPE table: tab[r*32+m] = (cos(r*inv[m]), sin(r*inv[m])) ----------------
__global__ void k_tab(float2* __restrict__ tab) {
    int idx = blockIdx.x * 256 + threadIdx.x;   // 8192 entries
    if (idx >= 256 * 32) return;
    int r = idx >> 5, m = idx & 31;
    float inv = expf(-((2.0f * (float)m) / 64.0f) * logf(10000.0f));
    float s, c;
    sincosf((float)r * inv, &s, &c);
    tab[idx] = make_float2(c, s);
}

// ---------------- K0b: transpose w_proj (64x128) -> wpt (128x64) ----------------
__global__ void k_wt(const float* __restrict__ wp, float* __restrict__ wpt) {
    int t = blockIdx.x * 256 + threadIdx.x;
    if (t >= 64 * 128) return;
    int o = t >> 7, cc = t & 127;
    wpt[cc * 64 + o] = wp[o * 128 + cc];
}

// ---------------- K1: fused 1x1 expand + depthwise 3x3 (VERIFIED R9 VERSION) ----------------
// R9: weights from LDS (uniform ds_read_b128), 2 positions/thread, CHB=32. 147us/dispatch.
// R10 post-mortem: 2-deep reg double-buffer on x REGRESSED (1327us total, likely spill) and
// tripped the replay-determinism wire -> reverted byte-for-byte to R9. k_expdw plateau.
__global__ __launch_bounds__(256) void k_expdw(const float* __restrict__ xb,
                                               const float* __restrict__ wh,
                                               const float* __restrict__ wdw,
                                               float* __restrict__ h2s,
                                               int r0, int R, int tiles_y) {
    __shared__ float hs[TW * TH * HPAD];   // 512*20*4B = 40KB
    __shared__ float wl[CHB * 64];         // 8KB: wl[o*64+i], 1x1 weights for this os-slice
    __shared__ float wdl[9 * CHB];         // 1.2KB: wdl[k*CHB+ch], dw taps transposed
    int t = threadIdx.x;
    int tx = t & 15, ty0 = t >> 4;         // ty0 in [0,16)
    int blk = blockIdx.x;
    int os = blk % OSPLIT;                 // fastest: 12 adjacent blocks share the x tile (L2)
    int rest = blk / OSPLIT;
    int txi = rest % 19;
    int tyi = rest / 19;
    int c = txi * 14 - 1 + tx;
    int rA = r0 + tyi * 30 - 1 + ty0;      // position A: tile row ty0
    int rB = rA + 16;                      // position B: tile row ty0+16
    int ccl = min(max(c, 0), 255);
    int rclA = min(max(rA, 0), 255), rclB = min(max(rB, 0), 255);
    const float* xpA = xb + rclA * 256 + ccl;
    const float* xpB = xb + rclB * 256 + ccl;

    // stage weights to LDS (one time per block)
    {
        const float* wsrc = wh + (os * CHB) * 64;          // 2048 floats
#pragma unroll
        for (int u = 0; u < 8; u++) wl[u * 256 + t] = wsrc[u * 256 + t];
        for (int u = t; u < 9 * CHB; u += 256) {           // 288 floats, transpose to [k][ch]
            int k = u >> 5, ch = u & 31;
            wdl[u] = wdw[(os * CHB + ch) * 9 + k];         // wdl[k*CHB+ch], u == k*32+ch
        }
    }
    __syncthreads();

    float accA[CHB], accB[CHB];
#pragma unroll
    for (int o = 0; o < CHB; o++) { accA[o] = 0.f; accB[o] = 0.f; }

    // streaming 1x1: 8 chunks of 8 input channels; weights broadcast from LDS
    for (int ib = 0; ib < 8; ib++) {
        float xa[8], xbv[8];
#pragma unroll
        for (int j = 0; j < 8; j++) {
            xa[j]  = xpA[(size_t)(ib * 8 + j) * HW];
            xbv[j] = xpB[(size_t)(ib * 8 + j) * HW];
        }
#pragma unroll
        for (int o = 0; o < CHB; o++) {
            const float* wr = &wl[o * 64 + ib * 8];
            float4 w0 = *(const float4*)wr;        // ds_read_b128, uniform -> broadcast
            float4 w1 = *(const float4*)(wr + 4);
            float a = accA[o], b = accB[o];
            a = fmaf(w0.x, xa[0], a);  b = fmaf(w0.x, xbv[0], b);
            a = fmaf(w0.y, xa[1], a);  b = fmaf(w0.y, xbv[1], b);
            a = fmaf(w0.z, xa[2], a);  b = fmaf(w0.z, xbv[2], b);
            a = fmaf(w0.w, xa[3], a);  b = fmaf(w0.w, xbv[3], b);
            a = fmaf(w1.x, xa[4], a);  b = fmaf(w1.x, xbv[4], b);
            a = fmaf(w1.y, xa[5], a);  b = fmaf(w1.y, xbv[5], b);
            a = fmaf(w1.z, xa[6], a);  b = fmaf(w1.z, xbv[6], b);
            a = fmaf(w1.w, xa[7], a);  b = fmaf(w1.w, xbv[7], b);
            accA[o] = a; accB[o] = b;
        }
    }

    // dw exchange + conv, chunked in 16-channel halves to keep LDS bounded
    bool colInt = (tx >= 1 && tx <= 14 && c < 256);
    bool intA = colInt && (ty0 >= 1) && (rA < r0 + R) && (rA < 256);
    bool intB = colInt && (ty0 <= 14) && (rB < r0 + R) && (rB < 256);
    int pA = ty0 * TW + tx, pB = pA + 256;
    size_t SR = (size_t)R * 256;

#pragma unroll
    for (int cc2 = 0; cc2 < 2; cc2++) {
        // write this chunk's 16 channels for both positions
#pragma unroll
        for (int q = 0; q < 4; q++) {
            int ch = cc2 * HCH + q * 4;
            *(float4*)&hs[pA * HPAD + q * 4] =
                make_float4(accA[ch + 0], accA[ch + 1], accA[ch + 2], accA[ch + 3]);
            *(float4*)&hs[pB * HPAD + q * 4] =
                make_float4(accB[ch + 0], accB[ch + 1], accB[ch + 2], accB[ch + 3]);
        }
        __syncthreads();
        // depthwise 3x3 for interior positions (taps broadcast from LDS)
#pragma unroll
        for (int side = 0; side < 2; side++) {
            bool act = side ? intB : intA;
            int p = side ? pB : pA;
            int r = side ? rB : rA;
            if (act) {
                size_t base = (size_t)(r - r0) * 256 + c;
#pragma unroll
                for (int q = 0; q < 4; q++) {
                    int ch = cc2 * HCH + q * 4;
                    float4 a = make_float4(0.f, 0.f, 0.f, 0.f);
#pragma unroll
                    for (int dr = -1; dr <= 1; dr++) {
                        int rr = r + dr;
                        if (rr < 0 || rr > 255) continue;
#pragma unroll
                        for (int dc = -1; dc <= 1; dc++) {
                            int cn = c + dc;
                            if (cn < 0 || cn > 255) continue;
                            float4 h = *(const float4*)&hs[(p + dr * TW + dc) * HPAD + q * 4];
                            int kidx = (dr + 1) * 3 + (dc + 1);
                            float4 wt = *(const float4*)&wdl[kidx * CHB + ch];  // uniform b128
                            a.x = fmaf(wt.x, h.x, a.x);
                            a.y = fmaf(wt.y, h.y, a.y);
                            a.z = fmaf(wt.z, h.z, a.z);
                            a.w = fmaf(wt.w, h.w, a.w);
                        }
                    }
                    int o0 = os * CHB + ch;
                    h2s[(size_t)(o0 + 0) * SR + base] = a.x;
                    h2s[(size_t)(o0 + 1) * SR + base] = a.y;
                    h2s[(size_t)(o0 + 2) * SR + base] = a.z;
                    h2s[(size_t)(o0 + 3) * SR + base] = a.w;
                }
            }
        }
        __syncthreads();
    }
}

// ---------------- K2: fused per-patch, 512 threads ----------------
// R11: k_patch was 2 blocks/CU (72KB LDS) x 4 waves = 2 waves/SIMD, 11 barriers -> drains
// exposed (R5 lesson). 512 threads/block, same one-patch work: LDS unchanged -> still 2
// blocks/CU but 16 waves/CU = 4 waves/SIMD; per-thread work halves. Index maps re-derived
// for T=512 (8 reduction groups of 16 ch; phase2: 2 tasks/thread; phase6: 8 pos/thread).
__global__ __launch_bounds__(512) void k_patch(const float* __restrict__ h2s,
                                               const float* __restrict__ gq,
                                               const float* __restrict__ gk,
                                               const float* __restrict__ gn,
                                               const float* __restrict__ wpt,
                                               const float2* __restrict__ tab,
                                               float* __restrict__ outb,
                                               int r0, int R) {
    __shared__ float qs[C2 * CST];
    __shared__ float ks[C2 * CST];
    __shared__ float part[512], part2[512];
    __shared__ float sq[64], sk[64], scal[64];
    int t = threadIdx.x;
    int p = blockIdx.x;                 // (R/8)*32 patches
    int prs = p >> 5, pc = p & 31;
    size_t SR = (size_t)R * 256;
    size_t sb = (size_t)(prs * 8) * 256 + pc * 8;
    const float* qg = h2s + sb;
    const float* kg = h2s + 128 * SR + sb;
    const float* vg = h2s + 256 * SR + sb;

    // phase 1: load q,k patch to LDS (2048 float4-pairs, 4 iters @ 512 thr)
    for (int it = 0; it < 4; it++) {
        int l4 = it * 512 + t;
        int c = l4 >> 4, r4 = l4 & 15;
        int i = r4 >> 1, jq = r4 & 1;
        *(float4*)&qs[c * CST + i * 8 + jq * 4] = *(const float4*)(qg + (size_t)c * SR + i * 256 + jq * 4);
        *(float4*)&ks[c * CST + i * 8 + jq * 4] = *(const float4*)(kg + (size_t)c * SR + i * 256 + jq * 4);
    }
    __syncthreads();

    // phase 1b: per-position channel sums of q^2, k^2 (8 groups x 16 ch)
    {
        int pos = t & 63, grp = t >> 6;    // grp in [0,8)
        float s1 = 0.f, s2 = 0.f;
        for (int c = grp * 16; c < grp * 16 + 16; c++) {
            float a = qs[c * CST + pos]; s1 = fmaf(a, a, s1);
            float e = ks[c * CST + pos]; s2 = fmaf(e, e, s2);
        }
        part[grp * 64 + pos] = s1;
        part2[grp * 64 + pos] = s2;
    }
    __syncthreads();
    if (t < 64) {
        float s = part[t] + part[64 + t] + part[128 + t] + part[192 + t] +
                  part[256 + t] + part[320 + t] + part[384 + t] + part[448 + t];
        sq[t] = rsqrtf(s * (1.f / 128.f) + EPS);
    } else if (t < 128) {
        int u = t - 64;
        float s = part2[u] + part2[64 + u] + part2[128 + u] + part2[192 + u] +
                  part2[256 + u] + part2[320 + u] + part2[384 + u] + part2[448 + u];
        sk[u] = rsqrtf(s * (1.f / 128.f) + EPS);
    }
    __syncthreads();

    // phase 1c: RMS-scale + RoPE in place (4096 tasks, 8 iters @ 512 thr)
    for (int u = 0; u < 8; u++) {
        int task = u * 512 + t;
        int m = task >> 6, pos = task & 63;
        int i = pos >> 3, j = pos & 7;
        float2 cs = (m < 32) ? tab[(r0 + prs * 8 + i) * 32 + m]
                             : tab[(pc * 8 + j) * 32 + (m - 32)];
        float sqp = sq[pos], skp = sk[pos];
        float q0 = qs[(2 * m) * CST + pos], q1 = qs[(2 * m + 1) * CST + pos];
        float y0 = gq[2 * m] * q0 * sqp, y1 = gq[2 * m + 1] * q1 * sqp;
        qs[(2 * m) * CST + pos] = y0 * cs.x - y1 * cs.y;
        qs[(2 * m + 1) * CST + pos] = y1 * cs.x + y0 * cs.y;
        float k0 = ks[(2 * m) * CST + pos], k1 = ks[(2 * m + 1) * CST + pos];
        float z0 = gk[2 * m] * k0 * skp, z1 = gk[2 * m + 1] * k1 * skp;
        ks[(2 * m) * CST + pos] = z0 * cs.x - z1 * cs.y;
        ks[(2 * m + 1) * CST + pos] = z1 * cs.x + z0 * cs.y;
    }
    __syncthreads();

    // phase 2: circular conv rows -> registers (1024 tasks, 2 per thread)
    float creg[2][8];
#pragma unroll
    for (int g4 = 0; g4 < 2; g4++) {
        int task = g4 * 512 + t;
        int c = task >> 3, m = task & 7;
        float o8[8] = {0, 0, 0, 0, 0, 0, 0, 0};
#pragma unroll
        for (int i = 0; i < 8; i++) {
            const float* qr = &qs[c * CST + i * 8];
            float4 qa = *(const float4*)qr, qb = *(const float4*)(qr + 4);
            float qq[8] = {qa.x, qa.y, qa.z, qa.w, qb.x, qb.y, qb.z, qb.w};
            int kr = (m - i) & 7;
            const float* krp = &ks[c * CST + kr * 8];
            float4 ka = *(const float4*)krp, kb2 = *(const float4*)(krp + 4);
            float kk[8] = {ka.x, ka.y, ka.z, ka.w, kb2.x, kb2.y, kb2.z, kb2.w};
#pragma unroll
            for (int n = 0; n < 8; n++)
#pragma unroll
                for (int j = 0; j < 8; j++)
                    o8[n] = fmaf(qq[j], kk[(n - j) & 7], o8[n]);
        }
#pragma unroll
        for (int n = 0; n < 8; n++) creg[g4][n] = o8[n];
    }
    __syncthreads();

    // phase 3: store corr over qs
#pragma unroll
    for (int g4 = 0; g4 < 2; g4++) {
        int task = g4 * 512 + t;
        int c = task >> 3, m = task & 7;
        *(float4*)&qs[c * CST + m * 8] =
            make_float4(creg[g4][0], creg[g4][1], creg[g4][2], creg[g4][3]);
        *(float4*)&qs[c * CST + m * 8 + 4] =
            make_float4(creg[g4][4], creg[g4][5], creg[g4][6], creg[g4][7]);
    }
    __syncthreads();

    // phase 4: per-position sum of corr^2 (8 groups x 16 ch)
    {
        int pos = t & 63, q4 = t >> 6;
        float ssum = 0.f;
        for (int c = q4 * 16; c < q4 * 16 + 16; c++) {
            float v = qs[c * CST + pos];
            ssum = fmaf(v, v, ssum);
        }
        part[q4 * 64 + pos] = ssum;
    }
    __syncthreads();
    if (t < 64) {
        float s = part[t] + part[64 + t] + part[128 + t] + part[192 + t] +
                  part[256 + t] + part[320 + t] + part[384 + t] + part[448 + t];
        scal[t] = rsqrtf(s * (1.0f / 128.f) + EPS);
    }
    __syncthreads();

    // phase 5: tmod in place (2048 tasks, 4 iters)
    for (int it = 0; it < 4; it++) {
        int l4 = it * 512 + t;
        int c = l4 >> 4, r4 = l4 & 15;
        int i = r4 >> 1, jq = r4 & 1;
        float4 vv = *(const float4*)(vg + (size_t)c * SR + i * 256 + jq * 4);
        float4 sc4 = *(const float4*)&scal[r4 * 4];
        float g = gn[c];
        float4 cu = *(float4*)&qs[c * CST + r4 * 4];
        cu.x = cu.x * sc4.x * g * vv.x;
        cu.y = cu.y * sc4.y * g * vv.y;
        cu.z = cu.z * sc4.z * g * vv.z;
        cu.w = cu.w * sc4.w * g * vv.w;
        *(float4*)&qs[c * CST + r4 * 4] = cu;
    }
    __syncthreads();

    // phase 6: project 128->64 (o = t&63, 8 positions per thread), stage to ks[pos*CST+o]
    {
        int o = t & 63, pg = t >> 6;       // pg in [0,8)
        float acc[8];
#pragma unroll
        for (int u = 0; u < 8; u++) acc[u] = 0.f;
        for (int c = 0; c < C2; c++) {
            float w = wpt[c * 64 + o];
            const float* tp = &qs[c * CST + pg * 8];
#pragma unroll
            for (int u4 = 0; u4 < 2; u4++) {
                float4 tv = *(const float4*)(tp + u4 * 4);
                acc[u4 * 4 + 0] = fmaf(w, tv.x, acc[u4 * 4 + 0]);
                acc[u4 * 4 + 1] = fmaf(w, tv.y, acc[u4 * 4 + 1]);
                acc[u4 * 4 + 2] = fmaf(w, tv.z, acc[u4 * 4 + 2]);
                acc[u4 * 4 + 3] = fmaf(w, tv.w, acc[u4 * 4 + 3]);
            }
        }
#pragma unroll
        for (int u = 0; u < 8; u++) ks[(pg * 8 + u) * CST + o] = acc[u];
    }
    __syncthreads();

    // phase 7: coalesced out write (1024 tasks, 2 iters)
    float* og = outb + (size_t)r0 * 256 + sb;
    for (int it = 0; it < 2; it++) {
        int l4 = it * 512 + t;
        int o = l4 >> 4, r4 = l4 & 15;
        int i = r4 >> 1, jq = r4 & 1;
        int p0 = i * 8 + jq * 4;
        float4 vv = make_float4(ks[(p0 + 0) * CST + o], ks[(p0 + 1) * CST + o],
                                ks[(p0 + 2) * CST + o], ks[(p0 + 3) * CST + o]);
        *(float4*)(og + (size_t)o * HW + i * 256 + jq * 4) = vv;
    }
}

extern "C" void kernel_launch(void* const* d_in, const int* in_sizes, int n_in,
                              void* d_out, int out_size, void* d_ws, size_t ws_size,
                              hipStream_t stream) {
    const float* x   = (const float*)d_in[0];
    const float* wh  = (const float*)d_in[1];
    const float* wdw = (const float*)d_in[2];
    const float* wp  = (const float*)d_in[3];
    const float* gn  = (const float*)d_in[4];
    const float* gq  = (const float*)d_in[5];
    const float* gk  = (const float*)d_in[6];
    float* out = (float*)d_out;

    // ws layout (floats): tab[16384] | wpt[8192] | h2s[384 * R * 256]
    size_t avail = ws_size / 4;
    if (avail < (size_t)24576 + (size_t)C6 * 8 * 256) return;  // need at least R=8
    size_t rows_cap = (avail - 24576) / ((size_t)C6 * 256);
    int R = (rows_cap >= 256) ? 256 : (int)(rows_cap & ~(size_t)7);

    float* ws = (float*)d_ws;
    float2* tab = (float2*)ws;
    float* wpt  = ws + 16384;
    float* h2s  = ws + 24576;

    k_tab<<<32, 256, 0, stream>>>(tab);
    k_wt<<<32, 256, 0, stream>>>(wp, wpt);
    for (int b = 0; b < BB; b++) {
        const float* xb = x + (size_t)b * Cc * HW;
        float* outb = out + (size_t)b * Cc * HW;
        for (int r0 = 0; r0 < 256; r0 += R) {
            int Rc = (256 - r0 < R) ? (256 - r0) : R;
            int tiles_y = (Rc + 29) / 30;
            k_expdw<<<19 * tiles_y * OSPLIT, 256, 0, stream>>>(xb, wh, wdw, h2s, r0, Rc, tiles_y);
            k_patch<<<(Rc / 8) * 32, 512, 0, stream>>>(h2s, gq, gk, gn, wpt, tab, outb, r0, Rc);
        }
    }
}

// Round 12
// 979.653 us; speedup vs baseline: 1.0707x; 1.0707x over previous
//
#include <hip/hip_runtime.h>
#include <math.h>

#define BB 4
#define Cc 64
#define C2 128
#define C6 384
#define HW 65536
#define EPS 1e-6f
#define CST 68      // padded LDS channel stride (patch kernel)
#define OSPLIT 12   // output-channel split across blocks
#define CHB 32      // channels per block = 384/OSPLIT
#define HCH 8       // channels per dw-exchange chunk (4 chunks)
#define HPAD 12     // hs row stride in floats: 12p%32 cycles 8 quad-starts -> conflict-free b128
#define TW 16       // tile width (cols), interior 14
#define TH 32       // tile height (rows), interior 30

// ---------------- K0: RoPE table: tab[r*32+m] = (cos(r*inv[m]), sin(r*inv[m])) ----------------
__global__ void k_tab(float2* __restrict__ tab) {
    int idx = blockIdx.x * 256 + threadIdx.x;   // 8192 entries
    if (idx >= 256 * 32) return;
    int r = idx >> 5, m = idx & 31;
    float inv = expf(-((2.0f * (float)m) / 64.0f) * logf(10000.0f));
    float s, c;
    sincosf((float)r * inv, &s, &c);
    tab[idx] = make_float2(c, s);
}

// ---------------- K0b: transpose w_proj (64x128) -> wpt (128x64) ----------------
__global__ void k_wt(const float* __restrict__ wp, float* __restrict__ wpt) {
    int t = blockIdx.x * 256 + threadIdx.x;
    if (t >= 64 * 128) return;
    int o = t >> 7, cc = t & 127;
    wpt[cc * 64 + o] = wp[o * 128 + cc];
}

// ---------------- K1: fused 1x1 expand + depthwise 3x3 ----------------
// R9: weights from LDS, 2 positions/thread, CHB=32 -> 147us, VALU 51%, occ 29% (3 blk/CU,
// LDS 49.5KB). Residual stall: x-load latency + 2.67-round tail. R10's reg-pipeline fix
// spilled (reverted). R12: attack the same stall via occupancy — dw exchange chunked
// 4 x 8ch so hs drops 40KB -> 24KB, total LDS 34KB -> 4 blocks/CU; at VGPR=68 the reg
// pool allows exactly 16 waves/CU, so LDS and VGPR limits align at 4 waves/SIMD.
// Concurrency 768 -> 1024 blocks (tail 2.67 -> 2.0 rounds). 8 barriers now, but +33% TLP.
__global__ __launch_bounds__(256) void k_expdw(const float* __restrict__ xb,
                                               const float* __restrict__ wh,
                                               const float* __restrict__ wdw,
                                               float* __restrict__ h2s,
                                               int r0, int R, int tiles_y) {
    __shared__ float hs[TW * TH * HPAD];   // 512*12*4B = 24KB
    __shared__ float wl[CHB * 64];         // 8KB: wl[o*64+i], 1x1 weights for this os-slice
    __shared__ float wdl[9 * CHB];         // 1.2KB: wdl[k*CHB+ch], dw taps transposed
    int t = threadIdx.x;
    int tx = t & 15, ty0 = t >> 4;         // ty0 in [0,16)
    int blk = blockIdx.x;
    int os = blk % OSPLIT;                 // fastest: 12 adjacent blocks share the x tile (L2)
    int rest = blk / OSPLIT;
    int txi = rest % 19;
    int tyi = rest / 19;
    int c = txi * 14 - 1 + tx;
    int rA = r0 + tyi * 30 - 1 + ty0;      // position A: tile row ty0
    int rB = rA + 16;                      // position B: tile row ty0+16
    int ccl = min(max(c, 0), 255);
    int rclA = min(max(rA, 0), 255), rclB = min(max(rB, 0), 255);
    const float* xpA = xb + rclA * 256 + ccl;
    const float* xpB = xb + rclB * 256 + ccl;

    // stage weights to LDS (one time per block)
    {
        const float* wsrc = wh + (os * CHB) * 64;          // 2048 floats
#pragma unroll
        for (int u = 0; u < 8; u++) wl[u * 256 + t] = wsrc[u * 256 + t];
        for (int u = t; u < 9 * CHB; u += 256) {           // 288 floats, transpose to [k][ch]
            int k = u >> 5, ch = u & 31;
            wdl[u] = wdw[(os * CHB + ch) * 9 + k];         // wdl[k*CHB+ch], u == k*32+ch
        }
    }
    __syncthreads();

    float accA[CHB], accB[CHB];
#pragma unroll
    for (int o = 0; o < CHB; o++) { accA[o] = 0.f; accB[o] = 0.f; }

    // streaming 1x1: 8 chunks of 8 input channels; weights broadcast from LDS
    for (int ib = 0; ib < 8; ib++) {
        float xa[8], xbv[8];
#pragma unroll
        for (int j = 0; j < 8; j++) {
            xa[j]  = xpA[(size_t)(ib * 8 + j) * HW];
            xbv[j] = xpB[(size_t)(ib * 8 + j) * HW];
        }
#pragma unroll
        for (int o = 0; o < CHB; o++) {
            const float* wr = &wl[o * 64 + ib * 8];
            float4 w0 = *(const float4*)wr;        // ds_read_b128, uniform -> broadcast
            float4 w1 = *(const float4*)(wr + 4);
            float a = accA[o], b = accB[o];
            a = fmaf(w0.x, xa[0], a);  b = fmaf(w0.x, xbv[0], b);
            a = fmaf(w0.y, xa[1], a);  b = fmaf(w0.y, xbv[1], b);
            a = fmaf(w0.z, xa[2], a);  b = fmaf(w0.z, xbv[2], b);
            a = fmaf(w0.w, xa[3], a);  b = fmaf(w0.w, xbv[3], b);
            a = fmaf(w1.x, xa[4], a);  b = fmaf(w1.x, xbv[4], b);
            a = fmaf(w1.y, xa[5], a);  b = fmaf(w1.y, xbv[5], b);
            a = fmaf(w1.z, xa[6], a);  b = fmaf(w1.z, xbv[6], b);
            a = fmaf(w1.w, xa[7], a);  b = fmaf(w1.w, xbv[7], b);
            accA[o] = a; accB[o] = b;
        }
    }

    // dw exchange + conv, chunked in 8-channel quarters (hs = 24KB -> 4 blocks/CU)
    bool colInt = (tx >= 1 && tx <= 14 && c < 256);
    bool intA = colInt && (ty0 >= 1) && (rA < r0 + R) && (rA < 256);
    bool intB = colInt && (ty0 <= 14) && (rB < r0 + R) && (rB < 256);
    int pA = ty0 * TW + tx, pB = pA + 256;
    size_t SR = (size_t)R * 256;

#pragma unroll
    for (int cc2 = 0; cc2 < 4; cc2++) {
        // write this chunk's 8 channels for both positions
#pragma unroll
        for (int q = 0; q < 2; q++) {
            int ch = cc2 * HCH + q * 4;
            *(float4*)&hs[pA * HPAD + q * 4] =
                make_float4(accA[ch + 0], accA[ch + 1], accA[ch + 2], accA[ch + 3]);
            *(float4*)&hs[pB * HPAD + q * 4] =
                make_float4(accB[ch + 0], accB[ch + 1], accB[ch + 2], accB[ch + 3]);
        }
        __syncthreads();
        // depthwise 3x3 for interior positions (taps broadcast from LDS)
#pragma unroll
        for (int side = 0; side < 2; side++) {
            bool act = side ? intB : intA;
            int p = side ? pB : pA;
            int r = side ? rB : rA;
            if (act) {
                size_t base = (size_t)(r - r0) * 256 + c;
#pragma unroll
                for (int q = 0; q < 2; q++) {
                    int ch = cc2 * HCH + q * 4;
                    float4 a = make_float4(0.f, 0.f, 0.f, 0.f);
#pragma unroll
                    for (int dr = -1; dr <= 1; dr++) {
                        int rr = r + dr;
                        if (rr < 0 || rr > 255) continue;
#pragma unroll
                        for (int dc = -1; dc <= 1; dc++) {
                            int cn = c + dc;
                            if (cn < 0 || cn > 255) continue;
                            float4 h = *(const float4*)&hs[(p + dr * TW + dc) * HPAD + q * 4];
                            int kidx = (dr + 1) * 3 + (dc + 1);
                            float4 wt = *(const float4*)&wdl[kidx * CHB + ch];  // uniform b128
                            a.x = fmaf(wt.x, h.x, a.x);
                            a.y = fmaf(wt.y, h.y, a.y);
                            a.z = fmaf(wt.z, h.z, a.z);
                            a.w = fmaf(wt.w, h.w, a.w);
                        }
                    }
                    int o0 = os * CHB + ch;
                    h2s[(size_t)(o0 + 0) * SR + base] = a.x;
                    h2s[(size_t)(o0 + 1) * SR + base] = a.y;
                    h2s[(size_t)(o0 + 2) * SR + base] = a.z;
                    h2s[(size_t)(o0 + 3) * SR + base] = a.w;
                }
            }
        }
        __syncthreads();
    }
}

// ---------------- K2: fused per-patch (VERIFIED R9 VERSION, 256 threads) ----------------
// R11 post-mortem: 512-thread variant REGRESSED (~+13us/dispatch) — 8-wave barrier arrival
// jitter with shorter phases. Reverted to the verified 256-thread form.
__global__ __launch_bounds__(256, 2) void k_patch(const float* __restrict__ h2s,
                                                  const float* __restrict__ gq,
                                                  const float* __restrict__ gk,
                                                  const float* __restrict__ gn,
                                                  const float* __restrict__ wpt,
                                                  const float2* __restrict__ tab,
                                                  float* __restrict__ outb,
                                                  int r0, int R) {
    __shared__ float qs[C2 * CST];
    __shared__ float ks[C2 * CST];
    __shared__ float part[256], part2[256];
    __shared__ float sq[64], sk[64], scal[64];
    int t = threadIdx.x;
    int p = blockIdx.x;                 // (R/8)*32 patches
    int prs = p >> 5, pc = p & 31;
    size_t SR = (size_t)R * 256;
    size_t sb = (size_t)(prs * 8) * 256 + pc * 8;
    const float* qg = h2s + sb;
    const float* kg = h2s + 128 * SR + sb;
    const float* vg = h2s + 256 * SR + sb;

    // phase 1: load q,k patch to LDS
    for (int it = 0; it < 8; it++) {
        int l4 = it * 256 + t;
        int c = l4 >> 4, r4 = l4 & 15;
        int i = r4 >> 1, jq = r4 & 1;
        *(float4*)&qs[c * CST + i * 8 + jq * 4] = *(const float4*)(qg + (size_t)c * SR + i * 256 + jq * 4);
        *(float4*)&ks[c * CST + i * 8 + jq * 4] = *(const float4*)(kg + (size_t)c * SR + i * 256 + jq * 4);
    }
    __syncthreads();

    // phase 1b: per-position channel sums of q^2, k^2
    {
        int pos = t & 63, grp = t >> 6;
        float s1 = 0.f, s2 = 0.f;
        for (int c = grp * 32; c < grp * 32 + 32; c++) {
            float a = qs[c * CST + pos]; s1 = fmaf(a, a, s1);
            float e = ks[c * CST + pos]; s2 = fmaf(e, e, s2);
        }
        part[grp * 64 + pos] = s1;
        part2[grp * 64 + pos] = s2;
    }
    __syncthreads();
    if (t < 64) {
        sq[t] = rsqrtf((part[t] + part[64 + t] + part[128 + t] + part[192 + t]) * (1.f / 128.f) + EPS);
    } else if (t < 128) {
        int u = t - 64;
        sk[u] = rsqrtf((part2[u] + part2[64 + u] + part2[128 + u] + part2[192 + u]) * (1.f / 128.f) + EPS);
    }
    __syncthreads();

    // phase 1c: RMS-scale + RoPE in place (pairs 2m,2m+1)
    for (int u = 0; u < 16; u++) {
        int task = u * 256 + t;
        int m = task >> 6, pos = task & 63;
        int i = pos >> 3, j = pos & 7;
        float2 cs = (m < 32) ? tab[(r0 + prs * 8 + i) * 32 + m]
                             : tab[(pc * 8 + j) * 32 + (m - 32)];
        float sqp = sq[pos], skp = sk[pos];
        float q0 = qs[(2 * m) * CST + pos], q1 = qs[(2 * m + 1) * CST + pos];
        float y0 = gq[2 * m] * q0 * sqp, y1 = gq[2 * m + 1] * q1 * sqp;
        qs[(2 * m) * CST + pos] = y0 * cs.x - y1 * cs.y;
        qs[(2 * m + 1) * CST + pos] = y1 * cs.x + y0 * cs.y;
        float k0 = ks[(2 * m) * CST + pos], k1 = ks[(2 * m + 1) * CST + pos];
        float z0 = gk[2 * m] * k0 * skp, z1 = gk[2 * m + 1] * k1 * skp;
        ks[(2 * m) * CST + pos] = z0 * cs.x - z1 * cs.y;
        ks[(2 * m + 1) * CST + pos] = z1 * cs.x + z0 * cs.y;
    }
    __syncthreads();

    // phase 2: circular conv rows -> registers (task = (c, m), 4 per thread; UNROLLED so creg
    // stays in VGPRs, not scratch)
    float creg[4][8];
#pragma unroll
    for (int g4 = 0; g4 < 4; g4++) {
        int task = g4 * 256 + t;
        int c = task >> 3, m = task & 7;
        float o8[8] = {0, 0, 0, 0, 0, 0, 0, 0};
#pragma unroll
        for (int i = 0; i < 8; i++) {
            const float* qr = &qs[c * CST + i * 8];
            float4 qa = *(const float4*)qr, qb = *(const float4*)(qr + 4);
            float qq[8] = {qa.x, qa.y, qa.z, qa.w, qb.x, qb.y, qb.z, qb.w};
            int kr = (m - i) & 7;
            const float* krp = &ks[c * CST + kr * 8];
            float4 ka = *(const float4*)krp, kb2 = *(const float4*)(krp + 4);
            float kk[8] = {ka.x, ka.y, ka.z, ka.w, kb2.x, kb2.y, kb2.z, kb2.w};
#pragma unroll
            for (int n = 0; n < 8; n++)
#pragma unroll
                for (int j = 0; j < 8; j++)
                    o8[n] = fmaf(qq[j], kk[(n - j) & 7], o8[n]);
        }
#pragma unroll
        for (int n = 0; n < 8; n++) creg[g4][n] = o8[n];
    }
    __syncthreads();

    // phase 3: store corr over qs
#pragma unroll
    for (int g4 = 0; g4 < 4; g4++) {
        int task = g4 * 256 + t;
        int c = task >> 3, m = task & 7;
        *(float4*)&qs[c * CST + m * 8] =
            make_float4(creg[g4][0], creg[g4][1], creg[g4][2], creg[g4][3]);
        *(float4*)&qs[c * CST + m * 8 + 4] =
            make_float4(creg[g4][4], creg[g4][5], creg[g4][6], creg[g4][7]);
    }
    __syncthreads();

    // phase 4: per-position sum of corr^2 over channels
    {
        int pos = t & 63, q4 = t >> 6;
        float ssum = 0.f;
        for (int c = q4 * 32; c < q4 * 32 + 32; c++) {
            float v = qs[c * CST + pos];
            ssum = fmaf(v, v, ssum);
        }
        part[q4 * 64 + pos] = ssum;
    }
    __syncthreads();
    if (t < 64) {
        float s = part[t] + part[64 + t] + part[128 + t] + part[192 + t];
        scal[t] = rsqrtf(s * (1.0f / 128.f) + EPS);
    }
    __syncthreads();

    // phase 5: tmod in place: qs[c][pos] = corr*scal[pos]*gn[c]*v[c][pos]
    for (int it = 0; it < 8; it++) {
        int l4 = it * 256 + t;
        int c = l4 >> 4, r4 = l4 & 15;
        int i = r4 >> 1, jq = r4 & 1;
        float4 vv = *(const float4*)(vg + (size_t)c * SR + i * 256 + jq * 4);
        float4 sc4 = *(const float4*)&scal[r4 * 4];
        float g = gn[c];
        float4 cu = *(float4*)&qs[c * CST + r4 * 4];
        cu.x = cu.x * sc4.x * g * vv.x;
        cu.y = cu.y * sc4.y * g * vv.y;
        cu.z = cu.z * sc4.z * g * vv.z;
        cu.w = cu.w * sc4.w * g * vv.w;
        *(float4*)&qs[c * CST + r4 * 4] = cu;
    }
    __syncthreads();

    // phase 6: project 128->64, stage to ks as out_s[pos*CST + o]
    {
        int o = t & 63, pg = t >> 6;
        float acc[16];
#pragma unroll
        for (int u = 0; u < 16; u++) acc[u] = 0.f;
        for (int c = 0; c < C2; c++) {
            float w = wpt[c * 64 + o];
            const float* tp = &qs[c * CST + pg * 16];
#pragma unroll
            for (int u4 = 0; u4 < 4; u4++) {
                float4 tv = *(const float4*)(tp + u4 * 4);
                acc[u4 * 4 + 0] = fmaf(w, tv.x, acc[u4 * 4 + 0]);
                acc[u4 * 4 + 1] = fmaf(w, tv.y, acc[u4 * 4 + 1]);
                acc[u4 * 4 + 2] = fmaf(w, tv.z, acc[u4 * 4 + 2]);
                acc[u4 * 4 + 3] = fmaf(w, tv.w, acc[u4 * 4 + 3]);
            }
        }
#pragma unroll
        for (int u = 0; u < 16; u++) ks[(pg * 16 + u) * CST + o] = acc[u];
    }
    __syncthreads();

    // phase 7: coalesced out write
    float* og = outb + (size_t)r0 * 256 + sb;
    for (int it = 0; it < 4; it++) {
        int l4 = it * 256 + t;
        int o = l4 >> 4, r4 = l4 & 15;
        int i = r4 >> 1, jq = r4 & 1;
        int p0 = i * 8 + jq * 4;
        float4 vv = make_float4(ks[(p0 + 0) * CST + o], ks[(p0 + 1) * CST + o],
                                ks[(p0 + 2) * CST + o], ks[(p0 + 3) * CST + o]);
        *(float4*)(og + (size_t)o * HW + i * 256 + jq * 4) = vv;
    }
}

extern "C" void kernel_launch(void* const* d_in, const int* in_sizes, int n_in,
                              void* d_out, int out_size, void* d_ws, size_t ws_size,
                              hipStream_t stream) {
    const float* x   = (const float*)d_in[0];
    const float* wh  = (const float*)d_in[1];
    const float* wdw = (const float*)d_in[2];
    const float* wp  = (const float*)d_in[3];
    const float* gn  = (const float*)d_in[4];
    const float* gq  = (const float*)d_in[5];
    const float* gk  = (const float*)d_in[6];
    float* out = (float*)d_out;

    // ws layout (floats): tab[16384] | wpt[8192] | h2s[384 * R * 256]
    size_t avail = ws_size / 4;
    if (avail < (size_t)24576 + (size_t)C6 * 8 * 256) return;  // need at least R=8
    size_t rows_cap = (avail - 24576) / ((size_t)C6 * 256);
    int R = (rows_cap >= 256) ? 256 : (int)(rows_cap & ~(size_t)7);

    float* ws = (float*)d_ws;
    float2* tab = (float2*)ws;
    float* wpt  = ws + 16384;
    float* h2s  = ws + 24576;

    k_tab<<<32, 256, 0, stream>>>(tab);
    k_wt<<<32, 256, 0, stream>>>(wp, wpt);
    for (int b = 0; b < BB; b++) {
        const float* xb = x + (size_t)b * Cc * HW;
        float* outb = out + (size_t)b * Cc * HW;
        for (int r0 = 0; r0 < 256; r0 += R) {
            int Rc = (256 - r0 < R) ? (256 - r0) : R;
            int tiles_y = (Rc + 29) / 30;
            k_expdw<<<19 * tiles_y * OSPLIT, 256, 0, stream>>>(xb, wh, wdw, h2s, r0, Rc, tiles_y);
            k_patch<<<(Rc / 8) * 32, 256, 0, stream>>>(h2s, gq, gk, gn, wpt, tab, outb, r0, Rc);
        }
    }
}

// Round 13
// 963.401 us; speedup vs baseline: 1.0888x; 1.0169x over previous
//
#include <hip/hip_runtime.h>
#include <math.h>

#define BB 4
#define Cc 64
#define C2 128
#define C6 384
#define HW 65536
#define EPS 1e-6f
#define CST 68      // padded LDS channel stride (patch kernel)
#define OST 65      // out-staging stride [o][pos]: bank=(o+pos)%32 -> 2-way everywhere (free)
#define OSPLIT 12   // output-channel split across blocks
#define CHB 32      // channels per block = 384/OSPLIT
#define HCH 8       // channels per dw-exchange chunk (4 chunks)
#define HPAD 12     // hs row stride in floats: 12p%32 cycles 8 quad-starts -> conflict-free b128
#define TW 16       // tile width (cols), interior 14
#define TH 32       // tile height (rows), interior 30

// ---------------- K0: RoPE table: tab[r*32+m] = (cos(r*inv[m]), sin(r*inv[m])) ----------------
__global__ void k_tab(float2* __restrict__ tab) {
    int idx = blockIdx.x * 256 + threadIdx.x;   // 8192 entries
    if (idx >= 256 * 32) return;
    int r = idx >> 5, m = idx & 31;
    float inv = expf(-((2.0f * (float)m) / 64.0f) * logf(10000.0f));
    float s, c;
    sincosf((float)r * inv, &s, &c);
    tab[idx] = make_float2(c, s);
}

// ---------------- K0b: transpose w_proj (64x128) -> wpt (128x64) ----------------
__global__ void k_wt(const float* __restrict__ wp, float* __restrict__ wpt) {
    int t = blockIdx.x * 256 + threadIdx.x;
    if (t >= 64 * 128) return;
    int o = t >> 7, cc = t & 127;
    wpt[cc * 64 + o] = wp[o * 128 + cc];
}

// ---------------- K1: fused 1x1 expand + depthwise 3x3 ----------------
// R12 (172us profiled, VALU 44%, occ 39%): 1x1 loop still x-load-latency-bound. Structural
// cause: the 12 os-blocks sharing an x-tile were CONSECUTIVE blockIdx -> round-robin over
// 8 XCDs -> share only L3 (~400-600cy), never L2. R13: XCD-aware swizzle — blk decodes as
// xcd + 8*(os + 12*tin), tile = xcd*TPX + tin, so all 12 sharers land on ONE XCD within a
// 96-block dispatch window -> x tile L2-resident (~200cy) for 11 of 12 blocks. Worst case
// (wrong %8 map): pure reorder, no loss. Grid padded to 96*TPX; dead blocks exit early.
__global__ __launch_bounds__(256) void k_expdw(const float* __restrict__ xb,
                                               const float* __restrict__ wh,
                                               const float* __restrict__ wdw,
                                               float* __restrict__ h2s,
                                               int r0, int R, int tiles_y) {
    __shared__ float hs[TW * TH * HPAD];   // 512*12*4B = 24KB
    __shared__ float wl[CHB * 64];         // 8KB: wl[o*64+i], 1x1 weights for this os-slice
    __shared__ float wdl[9 * CHB];         // 1.2KB: wdl[k*CHB+ch], dw taps transposed
    int t = threadIdx.x;
    int tx = t & 15, ty0 = t >> 4;         // ty0 in [0,16)
    int blk = blockIdx.x;
    int TPX = gridDim.x / 96;              // tiles per XCD slot
    int xcd = blk & 7;
    int rem = blk >> 3;
    int os = rem % OSPLIT;
    int tin = rem / OSPLIT;                // 0..TPX-1
    int tile = xcd * TPX + tin;
    int ntiles = 19 * tiles_y;
    if (tile >= ntiles) return;            // padded dead block (before any barrier)
    int txi = tile % 19;
    int tyi = tile / 19;
    int c = txi * 14 - 1 + tx;
    int rA = r0 + tyi * 30 - 1 + ty0;      // position A: tile row ty0
    int rB = rA + 16;                      // position B: tile row ty0+16
    int ccl = min(max(c, 0), 255);
    int rclA = min(max(rA, 0), 255), rclB = min(max(rB, 0), 255);
    const float* xpA = xb + rclA * 256 + ccl;
    const float* xpB = xb + rclB * 256 + ccl;

    // stage weights to LDS (one time per block)
    {
        const float* wsrc = wh + (os * CHB) * 64;          // 2048 floats
#pragma unroll
        for (int u = 0; u < 8; u++) wl[u * 256 + t] = wsrc[u * 256 + t];
        for (int u = t; u < 9 * CHB; u += 256) {           // 288 floats, transpose to [k][ch]
            int k = u >> 5, ch = u & 31;
            wdl[u] = wdw[(os * CHB + ch) * 9 + k];         // wdl[k*CHB+ch], u == k*32+ch
        }
    }
    __syncthreads();

    float accA[CHB], accB[CHB];
#pragma unroll
    for (int o = 0; o < CHB; o++) { accA[o] = 0.f; accB[o] = 0.f; }

    // streaming 1x1: 8 chunks of 8 input channels; weights broadcast from LDS
    for (int ib = 0; ib < 8; ib++) {
        float xa[8], xbv[8];
#pragma unroll
        for (int j = 0; j < 8; j++) {
            xa[j]  = xpA[(size_t)(ib * 8 + j) * HW];
            xbv[j] = xpB[(size_t)(ib * 8 + j) * HW];
        }
#pragma unroll
        for (int o = 0; o < CHB; o++) {
            const float* wr = &wl[o * 64 + ib * 8];
            float4 w0 = *(const float4*)wr;        // ds_read_b128, uniform -> broadcast
            float4 w1 = *(const float4*)(wr + 4);
            float a = accA[o], b = accB[o];
            a = fmaf(w0.x, xa[0], a);  b = fmaf(w0.x, xbv[0], b);
            a = fmaf(w0.y, xa[1], a);  b = fmaf(w0.y, xbv[1], b);
            a = fmaf(w0.z, xa[2], a);  b = fmaf(w0.z, xbv[2], b);
            a = fmaf(w0.w, xa[3], a);  b = fmaf(w0.w, xbv[3], b);
            a = fmaf(w1.x, xa[4], a);  b = fmaf(w1.x, xbv[4], b);
            a = fmaf(w1.y, xa[5], a);  b = fmaf(w1.y, xbv[5], b);
            a = fmaf(w1.z, xa[6], a);  b = fmaf(w1.z, xbv[6], b);
            a = fmaf(w1.w, xa[7], a);  b = fmaf(w1.w, xbv[7], b);
            accA[o] = a; accB[o] = b;
        }
    }

    // dw exchange + conv, chunked in 8-channel quarters (hs = 24KB -> 4 blocks/CU)
    bool colInt = (tx >= 1 && tx <= 14 && c < 256);
    bool intA = colInt && (ty0 >= 1) && (rA < r0 + R) && (rA < 256);
    bool intB = colInt && (ty0 <= 14) && (rB < r0 + R) && (rB < 256);
    int pA = ty0 * TW + tx, pB = pA + 256;
    size_t SR = (size_t)R * 256;

#pragma unroll
    for (int cc2 = 0; cc2 < 4; cc2++) {
        // write this chunk's 8 channels for both positions
#pragma unroll
        for (int q = 0; q < 2; q++) {
            int ch = cc2 * HCH + q * 4;
            *(float4*)&hs[pA * HPAD + q * 4] =
                make_float4(accA[ch + 0], accA[ch + 1], accA[ch + 2], accA[ch + 3]);
            *(float4*)&hs[pB * HPAD + q * 4] =
                make_float4(accB[ch + 0], accB[ch + 1], accB[ch + 2], accB[ch + 3]);
        }
        __syncthreads();
        // depthwise 3x3 for interior positions (taps broadcast from LDS)
#pragma unroll
        for (int side = 0; side < 2; side++) {
            bool act = side ? intB : intA;
            int p = side ? pB : pA;
            int r = side ? rB : rA;
            if (act) {
                size_t base = (size_t)(r - r0) * 256 + c;
#pragma unroll
                for (int q = 0; q < 2; q++) {
                    int ch = cc2 * HCH + q * 4;
                    float4 a = make_float4(0.f, 0.f, 0.f, 0.f);
#pragma unroll
                    for (int dr = -1; dr <= 1; dr++) {
                        int rr = r + dr;
                        if (rr < 0 || rr > 255) continue;
#pragma unroll
                        for (int dc = -1; dc <= 1; dc++) {
                            int cn = c + dc;
                            if (cn < 0 || cn > 255) continue;
                            float4 h = *(const float4*)&hs[(p + dr * TW + dc) * HPAD + q * 4];
                            int kidx = (dr + 1) * 3 + (dc + 1);
                            float4 wt = *(const float4*)&wdl[kidx * CHB + ch];  // uniform b128
                            a.x = fmaf(wt.x, h.x, a.x);
                            a.y = fmaf(wt.y, h.y, a.y);
                            a.z = fmaf(wt.z, h.z, a.z);
                            a.w = fmaf(wt.w, h.w, a.w);
                        }
                    }
                    int o0 = os * CHB + ch;
                    h2s[(size_t)(o0 + 0) * SR + base] = a.x;
                    h2s[(size_t)(o0 + 1) * SR + base] = a.y;
                    h2s[(size_t)(o0 + 2) * SR + base] = a.z;
                    h2s[(size_t)(o0 + 3) * SR + base] = a.w;
                }
            }
        }
        __syncthreads();
    }
}

// ---------------- K2: fused per-patch (256 threads) ----------------
// R13: PMC showed 7.18M SQ_LDS_BANK_CONFLICT — phase-7's ks[(p0+k)*68+o] gather puts the
// 16 lanes of an o-group on 2 banks (8-way x 16 reads). Fix: stage projection output as
// ks[o*OST + pos], OST=65 -> bank=(o+pos)%32: phase-6 writes 2-way (free), phase-7 reads
// uniform 2-way (free). Everything else identical to the verified R9 form.
__global__ __launch_bounds__(256, 2) void k_patch(const float* __restrict__ h2s,
                                                  const float* __restrict__ gq,
                                                  const float* __restrict__ gk,
                                                  const float* __restrict__ gn,
                                                  const float* __restrict__ wpt,
                                                  const float2* __restrict__ tab,
                                                  float* __restrict__ outb,
                                                  int r0, int R) {
    __shared__ float qs[C2 * CST];
    __shared__ float ks[C2 * CST];
    __shared__ float part[256], part2[256];
    __shared__ float sq[64], sk[64], scal[64];
    int t = threadIdx.x;
    int p = blockIdx.x;                 // (R/8)*32 patches
    int prs = p >> 5, pc = p & 31;
    size_t SR = (size_t)R * 256;
    size_t sb = (size_t)(prs * 8) * 256 + pc * 8;
    const float* qg = h2s + sb;
    const float* kg = h2s + 128 * SR + sb;
    const float* vg = h2s + 256 * SR + sb;

    // phase 1: load q,k patch to LDS
    for (int it = 0; it < 8; it++) {
        int l4 = it * 256 + t;
        int c = l4 >> 4, r4 = l4 & 15;
        int i = r4 >> 1, jq = r4 & 1;
        *(float4*)&qs[c * CST + i * 8 + jq * 4] = *(const float4*)(qg + (size_t)c * SR + i * 256 + jq * 4);
        *(float4*)&ks[c * CST + i * 8 + jq * 4] = *(const float4*)(kg + (size_t)c * SR + i * 256 + jq * 4);
    }
    __syncthreads();

    // phase 1b: per-position channel sums of q^2, k^2
    {
        int pos = t & 63, grp = t >> 6;
        float s1 = 0.f, s2 = 0.f;
        for (int c = grp * 32; c < grp * 32 + 32; c++) {
            float a = qs[c * CST + pos]; s1 = fmaf(a, a, s1);
            float e = ks[c * CST + pos]; s2 = fmaf(e, e, s2);
        }
        part[grp * 64 + pos] = s1;
        part2[grp * 64 + pos] = s2;
    }
    __syncthreads();
    if (t < 64) {
        sq[t] = rsqrtf((part[t] + part[64 + t] + part[128 + t] + part[192 + t]) * (1.f / 128.f) + EPS);
    } else if (t < 128) {
        int u = t - 64;
        sk[u] = rsqrtf((part2[u] + part2[64 + u] + part2[128 + u] + part2[192 + u]) * (1.f / 128.f) + EPS);
    }
    __syncthreads();

    // phase 1c: RMS-scale + RoPE in place (pairs 2m,2m+1)
    for (int u = 0; u < 16; u++) {
        int task = u * 256 + t;
        int m = task >> 6, pos = task & 63;
        int i = pos >> 3, j = pos & 7;
        float2 cs = (m < 32) ? tab[(r0 + prs * 8 + i) * 32 + m]
                             : tab[(pc * 8 + j) * 32 + (m - 32)];
        float sqp = sq[pos], skp = sk[pos];
        float q0 = qs[(2 * m) * CST + pos], q1 = qs[(2 * m + 1) * CST + pos];
        float y0 = gq[2 * m] * q0 * sqp, y1 = gq[2 * m + 1] * q1 * sqp;
        qs[(2 * m) * CST + pos] = y0 * cs.x - y1 * cs.y;
        qs[(2 * m + 1) * CST + pos] = y1 * cs.x + y0 * cs.y;
        float k0 = ks[(2 * m) * CST + pos], k1 = ks[(2 * m + 1) * CST + pos];
        float z0 = gk[2 * m] * k0 * skp, z1 = gk[2 * m + 1] * k1 * skp;
        ks[(2 * m) * CST + pos] = z0 * cs.x - z1 * cs.y;
        ks[(2 * m + 1) * CST + pos] = z1 * cs.x + z0 * cs.y;
    }
    __syncthreads();

    // phase 2: circular conv rows -> registers (task = (c, m), 4 per thread; UNROLLED so creg
    // stays in VGPRs, not scratch)
    float creg[4][8];
#pragma unroll
    for (int g4 = 0; g4 < 4; g4++) {
        int task = g4 * 256 + t;
        int c = task >> 3, m = task & 7;
        float o8[8] = {0, 0, 0, 0, 0, 0, 0, 0};
#pragma unroll
        for (int i = 0; i < 8; i++) {
            const float* qr = &qs[c * CST + i * 8];
            float4 qa = *(const float4*)qr, qb = *(const float4*)(qr + 4);
            float qq[8] = {qa.x, qa.y, qa.z, qa.w, qb.x, qb.y, qb.z, qb.w};
            int kr = (m - i) & 7;
            const float* krp = &ks[c * CST + kr * 8];
            float4 ka = *(const float4*)krp, kb2 = *(const float4*)(krp + 4);
            float kk[8] = {ka.x, ka.y, ka.z, ka.w, kb2.x, kb2.y, kb2.z, kb2.w};
#pragma unroll
            for (int n = 0; n < 8; n++)
#pragma unroll
                for (int j = 0; j < 8; j++)
                    o8[n] = fmaf(qq[j], kk[(n - j) & 7], o8[n]);
        }
#pragma unroll
        for (int n = 0; n < 8; n++) creg[g4][n] = o8[n];
    }
    __syncthreads();

    // phase 3: store corr over qs
#pragma unroll
    for (int g4 = 0; g4 < 4; g4++) {
        int task = g4 * 256 + t;
        int c = task >> 3, m = task & 7;
        *(float4*)&qs[c * CST + m * 8] =
            make_float4(creg[g4][0], creg[g4][1], creg[g4][2], creg[g4][3]);
        *(float4*)&qs[c * CST + m * 8 + 4] =
            make_float4(creg[g4][4], creg[g4][5], creg[g4][6], creg[g4][7]);
    }
    __syncthreads();

    // phase 4: per-position sum of corr^2 over channels
    {
        int pos = t & 63, q4 = t >> 6;
        float ssum = 0.f;
        for (int c = q4 * 32; c < q4 * 32 + 32; c++) {
            float v = qs[c * CST + pos];
            ssum = fmaf(v, v, ssum);
        }
        part[q4 * 64 + pos] = ssum;
    }
    __syncthreads();
    if (t < 64) {
        float s = part[t] + part[64 + t] + part[128 + t] + part[192 + t];
        scal[t] = rsqrtf(s * (1.0f / 128.f) + EPS);
    }
    __syncthreads();

    // phase 5: tmod in place: qs[c][pos] = corr*scal[pos]*gn[c]*v[c][pos]
    for (int it = 0; it < 8; it++) {
        int l4 = it * 256 + t;
        int c = l4 >> 4, r4 = l4 & 15;
        int i = r4 >> 1, jq = r4 & 1;
        float4 vv = *(const float4*)(vg + (size_t)c * SR + i * 256 + jq * 4);
        float4 sc4 = *(const float4*)&scal[r4 * 4];
        float g = gn[c];
        float4 cu = *(float4*)&qs[c * CST + r4 * 4];
        cu.x = cu.x * sc4.x * g * vv.x;
        cu.y = cu.y * sc4.y * g * vv.y;
        cu.z = cu.z * sc4.z * g * vv.z;
        cu.w = cu.w * sc4.w * g * vv.w;
        *(float4*)&qs[c * CST + r4 * 4] = cu;
    }
    __syncthreads();

    // phase 6: project 128->64, stage to ks as out_s[o*OST + pos] (conflict-free)
    {
        int o = t & 63, pg = t >> 6;
        float acc[16];
#pragma unroll
        for (int u = 0; u < 16; u++) acc[u] = 0.f;
        for (int c = 0; c < C2; c++) {
            float w = wpt[c * 64 + o];
            const float* tp = &qs[c * CST + pg * 16];
#pragma unroll
            for (int u4 = 0; u4 < 4; u4++) {
                float4 tv = *(const float4*)(tp + u4 * 4);
                acc[u4 * 4 + 0] = fmaf(w, tv.x, acc[u4 * 4 + 0]);
                acc[u4 * 4 + 1] = fmaf(w, tv.y, acc[u4 * 4 + 1]);
                acc[u4 * 4 + 2] = fmaf(w, tv.z, acc[u4 * 4 + 2]);
                acc[u4 * 4 + 3] = fmaf(w, tv.w, acc[u4 * 4 + 3]);
            }
        }
#pragma unroll
        for (int u = 0; u < 16; u++) ks[o * OST + pg * 16 + u] = acc[u];
    }
    __syncthreads();

    // phase 7: coalesced out write (reads out_s[o][pos] — 2-way banks, free)
    float* og = outb + (size_t)r0 * 256 + sb;
    for (int it = 0; it < 4; it++) {
        int l4 = it * 256 + t;
        int o = l4 >> 4, r4 = l4 & 15;
        int i = r4 >> 1, jq = r4 & 1;
        int p0 = i * 8 + jq * 4;
        const float* kp = &ks[o * OST + p0];
        float4 vv = make_float4(kp[0], kp[1], kp[2], kp[3]);
        *(float4*)(og + (size_t)o * HW + i * 256 + jq * 4) = vv;
    }
}

extern "C" void kernel_launch(void* const* d_in, const int* in_sizes, int n_in,
                              void* d_out, int out_size, void* d_ws, size_t ws_size,
                              hipStream_t stream) {
    const float* x   = (const float*)d_in[0];
    const float* wh  = (const float*)d_in[1];
    const float* wdw = (const float*)d_in[2];
    const float* wp  = (const float*)d_in[3];
    const float* gn  = (const float*)d_in[4];
    const float* gq  = (const float*)d_in[5];
    const float* gk  = (const float*)d_in[6];
    float* out = (float*)d_out;

    // ws layout (floats): tab[16384] | wpt[8192] | h2s[384 * R * 256]
    size_t avail = ws_size / 4;
    if (avail < (size_t)24576 + (size_t)C6 * 8 * 256) return;  // need at least R=8
    size_t rows_cap = (avail - 24576) / ((size_t)C6 * 256);
    int R = (rows_cap >= 256) ? 256 : (int)(rows_cap & ~(size_t)7);

    float* ws = (float*)d_ws;
    float2* tab = (float2*)ws;
    float* wpt  = ws + 16384;
    float* h2s  = ws + 24576;

    k_tab<<<32, 256, 0, stream>>>(tab);
    k_wt<<<32, 256, 0, stream>>>(wp, wpt);
    for (int b = 0; b < BB; b++) {
        const float* xb = x + (size_t)b * Cc * HW;
        float* outb = out + (size_t)b * Cc * HW;
        for (int r0 = 0; r0 < 256; r0 += R) {
            int Rc = (256 - r0 < R) ? (256 - r0) : R;
            int tiles_y = (Rc + 29) / 30;
            int ntiles = 19 * tiles_y;
            int TPX = (ntiles + 7) / 8;    // tiles per XCD slot
            k_expdw<<<96 * TPX, 256, 0, stream>>>(xb, wh, wdw, h2s, r0, Rc, tiles_y);
            k_patch<<<(Rc / 8) * 32, 256, 0, stream>>>(h2s, gq, gk, gn, wpt, tab, outb, r0, Rc);
        }
    }
}